// Round 1
// baseline (265.664 us; speedup 1.0000x reference)
//
#include <hip/hip_runtime.h>
#include <math.h>

#define ERRV 1e-6f
#define NB 24576
#define NE 128      // edges per rod
#define NV 129      // verts per rod
#define RODS_PER_BLOCK 4

struct Q4 { float w, x, y, z; };

__device__ __forceinline__ Q4 qident() { Q4 q; q.w = 1.f; q.x = 0.f; q.y = 0.f; q.z = 0.f; return q; }

// a ⊗ b : rotation "apply b first, then a"
__device__ __forceinline__ Q4 qmul(const Q4& a, const Q4& b) {
    Q4 r;
    r.w = a.w*b.w - a.x*b.x - a.y*b.y - a.z*b.z;
    r.x = a.w*b.x + b.w*a.x + a.y*b.z - a.z*b.y;
    r.y = a.w*b.y + b.w*a.y + a.z*b.x - a.x*b.z;
    r.z = a.w*b.z + b.w*a.z + a.x*b.y - a.y*b.x;
    return r;
}

__device__ __forceinline__ Q4 qshfl_up(const Q4& q, int delta) {
    Q4 r;
    r.w = __shfl_up(q.w, delta, 64);
    r.x = __shfl_up(q.x, delta, 64);
    r.y = __shfl_up(q.y, delta, 64);
    r.z = __shfl_up(q.z, delta, 64);
    return r;
}

__device__ __forceinline__ float3 cross3(const float3 a, const float3 b) {
    return make_float3(a.y*b.z - a.z*b.y, a.z*b.x - a.x*b.z, a.x*b.y - a.y*b.x);
}
__device__ __forceinline__ float dot3(const float3 a, const float3 b) {
    return a.x*b.x + a.y*b.y + a.z*b.z;
}

// quaternion for one edge from kb (exact port of reference math)
__device__ __forceinline__ Q4 quat_from_kb(const float3 kb) {
    float mag = dot3(kb, kb);
    float inv = 1.0f / (4.0f + mag);
    float w = sqrtf(4.0f * inv);          // cosPhi
    if (1.0f - w <= ERRV) return qident(); // reference: keep u_prev == identity rotation
    float s = sqrtf(mag * inv);           // sinPhi
    float n = sqrtf(mag);
    float sc = s / fmaxf(n, 1e-12f);      // sinPhi * normalize(kb)
    Q4 q; q.w = w; q.x = sc*kb.x; q.y = sc*kb.y; q.z = sc*kb.z;
    return q;
}

// rotate u0 by (re-normalized) quaternion q
__device__ __forceinline__ float3 qrot(const Q4 q, const float3 u) {
    float r = rsqrtf(q.w*q.w + q.x*q.x + q.y*q.y + q.z*q.z);
    float w = q.w * r;
    float3 v = make_float3(q.x*r, q.y*r, q.z*r);
    float3 t  = cross3(v, u);
    float3 t2 = cross3(v, t);
    return make_float3(u.x + 2.0f*(w*t.x + t2.x),
                       u.y + 2.0f*(w*t.y + t2.y),
                       u.z + 2.0f*(w*t.z + t2.z));
}

__global__ __launch_bounds__(256) void rod_frames_kernel(
    const float* __restrict__ verts,       // (B, 129, 3)
    const float* __restrict__ init_direct, // (B, 3)
    const float* __restrict__ m_theta,     // (B, 128)
    const float* __restrict__ edge_mask,   // (B, 128, 1)
    const float* __restrict__ restL,       // (B, 128)
    float* __restrict__ out)               // (B, 128, 5, 3)
{
    __shared__ __align__(16) float lds[RODS_PER_BLOCK * NE * 15]; // 7680 floats, reused for verts stage
    const int tid = threadIdx.x;
    const int wv  = tid >> 6;      // wave id = rod-in-block
    const int l   = tid & 63;      // lane: handles edges 2l, 2l+1
    const int b0  = blockIdx.x * RODS_PER_BLOCK;
    const int b   = b0 + wv;

    // ---- stage verts (4 consecutive rods = contiguous 1548 floats) ----
    for (int i = tid; i < RODS_PER_BLOCK * NV * 3; i += 256)
        lds[i] = verts[(size_t)b0 * (NV*3) + i];
    __syncthreads();

    float v[9];
    #pragma unroll
    for (int k = 0; k < 9; ++k) v[k] = lds[wv * (NV*3) + 6*l + k];
    __syncthreads();  // verts LDS region will be reused for output staging

    // edges 2l and 2l+1
    float3 eLo = make_float3(v[3]-v[0], v[4]-v[1], v[5]-v[2]);
    float3 eHi = make_float3(v[6]-v[3], v[7]-v[4], v[8]-v[5]);

    // rest lengths (coalesced float2)
    const float2 L2 = ((const float2*)(restL + (size_t)b * NE))[l];
    float Llo = L2.x, Lhi = L2.y;
    float Lprev = __shfl_up(Lhi, 1, 64);          // L[2l-1]
    float3 ePrev;
    ePrev.x = __shfl_up(eHi.x, 1, 64);
    ePrev.y = __shfl_up(eHi.y, 1, 64);
    ePrev.z = __shfl_up(eHi.z, 1, 64);            // edge 2l-1

    // kb for both edges
    float3 kbLo;
    if (l == 0) {
        kbLo = make_float3(0.f, 0.f, 0.f);        // kb[0] = 0
    } else {
        float den = Lprev * Llo + dot3(ePrev, eLo);
        float3 c = cross3(ePrev, eLo);
        float s = 2.0f / den;
        kbLo = make_float3(s*c.x, s*c.y, s*c.z);
    }
    float3 kbHi;
    {
        float den = Llo * Lhi + dot3(eLo, eHi);
        float3 c = cross3(eLo, eHi);
        float s = 2.0f / den;
        kbHi = make_float3(s*c.x, s*c.y, s*c.z);
    }

    // u0 = normalize(cross(cross(e0, init_direct), e0)); e0 = edge 0 (lane 0's eLo)
    float3 e0;
    e0.x = __shfl(eLo.x, 0, 64);
    e0.y = __shfl(eLo.y, 0, 64);
    e0.z = __shfl(eLo.z, 0, 64);
    float3 ind = make_float3(init_direct[(size_t)b*3 + 0],
                             init_direct[(size_t)b*3 + 1],
                             init_direct[(size_t)b*3 + 2]);
    float3 N0 = cross3(e0, ind);
    float3 u0 = cross3(N0, e0);
    {
        float n = sqrtf(dot3(u0, u0));
        float r = 1.0f / fmaxf(n, 1e-12f);
        u0 = make_float3(u0.x*r, u0.y*r, u0.z*r);
    }

    // per-edge quaternions; identity where (1-cosPhi)<=ERR (incl. edge 0)
    Q4 qLo = quat_from_kb(kbLo);
    Q4 qHi = quat_from_kb(kbHi);

    // wave-level inclusive prefix product: Q_e = q_e ⊗ ... ⊗ q_1
    Q4 T = qmul(qHi, qLo);      // this lane's pair product
    Q4 P = T;
    #pragma unroll
    for (int off = 1; off < 64; off <<= 1) {
        Q4 o = qshfl_up(P, off);
        if (l >= off) P = qmul(P, o);
    }
    Q4 E = qshfl_up(P, 1);      // exclusive prefix
    if (l == 0) E = qident();
    Q4 QLo = qmul(qLo, E);      // prefix through edge 2l
    Q4 QHi = qmul(qHi, QLo);    // prefix through edge 2l+1

    // material frame per edge
    float3 buLo = qrot(QLo, u0);
    float3 buHi = qrot(QHi, u0);

    float3 bvLo = cross3(eLo, buLo);
    { float n = sqrtf(dot3(bvLo,bvLo)); float r = 1.0f/fmaxf(n,1e-12f); bvLo = make_float3(bvLo.x*r,bvLo.y*r,bvLo.z*r); }
    float3 bvHi = cross3(eHi, buHi);
    { float n = sqrtf(dot3(bvHi,bvHi)); float r = 1.0f/fmaxf(n,1e-12f); bvHi = make_float3(bvHi.x*r,bvHi.y*r,bvHi.z*r); }

    const float2 M2 = ((const float2*)(edge_mask + (size_t)b * NE))[l];
    buLo.x *= M2.x; buLo.y *= M2.x; buLo.z *= M2.x;
    bvLo.x *= M2.x; bvLo.y *= M2.x; bvLo.z *= M2.x;
    buHi.x *= M2.y; buHi.y *= M2.y; buHi.z *= M2.y;
    bvHi.x *= M2.y; bvHi.y *= M2.y; bvHi.z *= M2.y;

    const float2 TH = ((const float2*)(m_theta + (size_t)b * NE))[l];
    float sLo, cLo, sHi, cHi;
    __sincosf(TH.x, &sLo, &cLo);
    __sincosf(TH.y, &sHi, &cHi);

    float3 m1Lo = make_float3(cLo*buLo.x + sLo*bvLo.x, cLo*buLo.y + sLo*bvLo.y, cLo*buLo.z + sLo*bvLo.z);
    float3 m2Lo = make_float3(-sLo*buLo.x + cLo*bvLo.x, -sLo*buLo.y + cLo*bvLo.y, -sLo*buLo.z + cLo*bvLo.z);
    float3 m1Hi = make_float3(cHi*buHi.x + sHi*bvHi.x, cHi*buHi.y + sHi*bvHi.y, cHi*buHi.z + sHi*bvHi.z);
    float3 m2Hi = make_float3(-sHi*buHi.x + cHi*bvHi.x, -sHi*buHi.y + cHi*bvHi.y, -sHi*buHi.z + cHi*bvHi.z);

    // ---- stage output: rod wv, edges 2l / 2l+1, layout (e,5,3) ----
    float* o = lds + wv * (NE*15) + 30*l;
    o[0]=buLo.x; o[1]=buLo.y; o[2]=buLo.z;
    o[3]=bvLo.x; o[4]=bvLo.y; o[5]=bvLo.z;
    o[6]=kbLo.x; o[7]=kbLo.y; o[8]=kbLo.z;
    o[9]=m1Lo.x; o[10]=m1Lo.y; o[11]=m1Lo.z;
    o[12]=m2Lo.x; o[13]=m2Lo.y; o[14]=m2Lo.z;
    o[15]=buHi.x; o[16]=buHi.y; o[17]=buHi.z;
    o[18]=bvHi.x; o[19]=bvHi.y; o[20]=bvHi.z;
    o[21]=kbHi.x; o[22]=kbHi.y; o[23]=kbHi.z;
    o[24]=m1Hi.x; o[25]=m1Hi.y; o[26]=m1Hi.z;
    o[27]=m2Hi.x; o[28]=m2Hi.y; o[29]=m2Hi.z;
    __syncthreads();

    // ---- coalesced float4 copy-out: 4 rods' outputs are contiguous ----
    const float4* s4 = (const float4*)lds;
    float4* o4 = (float4*)(out + (size_t)b0 * (NE*15));
    for (int i = tid; i < RODS_PER_BLOCK * NE * 15 / 4; i += 256)
        o4[i] = s4[i];
}

extern "C" void kernel_launch(void* const* d_in, const int* in_sizes, int n_in,
                              void* d_out, int out_size, void* d_ws, size_t ws_size,
                              hipStream_t stream) {
    const float* verts  = (const float*)d_in[0];
    const float* initd  = (const float*)d_in[1];
    const float* mtheta = (const float*)d_in[2];
    const float* emask  = (const float*)d_in[3];
    const float* restL  = (const float*)d_in[4];
    float* out = (float*)d_out;
    dim3 grid(NB / RODS_PER_BLOCK);   // 6144 blocks
    rod_frames_kernel<<<grid, 256, 0, stream>>>(verts, initd, mtheta, emask, restL, out);
}

// Round 3
// 247.803 us; speedup vs baseline: 1.0721x; 1.0721x over previous
//
#include <hip/hip_runtime.h>
#include <math.h>

#define ERRV 1e-6f
#define NB 24576
#define NE 128      // edges per rod
#define NV 129      // verts per rod
#define RODS_PER_BLOCK 4

typedef float v4f __attribute__((ext_vector_type(4)));  // clang-native for nontemporal builtins

struct Q4 { float w, x, y, z; };

__device__ __forceinline__ Q4 qident() { Q4 q; q.w = 1.f; q.x = 0.f; q.y = 0.f; q.z = 0.f; return q; }

// a ⊗ b : rotation "apply b first, then a"
__device__ __forceinline__ Q4 qmul(const Q4& a, const Q4& b) {
    Q4 r;
    r.w = a.w*b.w - a.x*b.x - a.y*b.y - a.z*b.z;
    r.x = a.w*b.x + b.w*a.x + a.y*b.z - a.z*b.y;
    r.y = a.w*b.y + b.w*a.y + a.z*b.x - a.x*b.z;
    r.z = a.w*b.z + b.w*a.z + a.x*b.y - a.y*b.x;
    return r;
}

__device__ __forceinline__ Q4 qshfl_up(const Q4& q, int delta) {
    Q4 r;
    r.w = __shfl_up(q.w, delta, 64);
    r.x = __shfl_up(q.x, delta, 64);
    r.y = __shfl_up(q.y, delta, 64);
    r.z = __shfl_up(q.z, delta, 64);
    return r;
}

__device__ __forceinline__ float3 cross3(const float3 a, const float3 b) {
    return make_float3(a.y*b.z - a.z*b.y, a.z*b.x - a.x*b.z, a.x*b.y - a.y*b.x);
}
__device__ __forceinline__ float dot3(const float3 a, const float3 b) {
    return a.x*b.x + a.y*b.y + a.z*b.z;
}

// quaternion for one edge from kb (exact port of reference math)
__device__ __forceinline__ Q4 quat_from_kb(const float3 kb) {
    float mag = dot3(kb, kb);
    float inv = 1.0f / (4.0f + mag);
    float w = sqrtf(4.0f * inv);          // cosPhi
    if (1.0f - w <= ERRV) return qident(); // reference: keep u_prev == identity rotation
    float s = sqrtf(mag * inv);           // sinPhi
    float n = sqrtf(mag);
    float sc = s / fmaxf(n, 1e-12f);      // sinPhi * normalize(kb)
    Q4 q; q.w = w; q.x = sc*kb.x; q.y = sc*kb.y; q.z = sc*kb.z;
    return q;
}

// rotate u0 by (re-normalized) quaternion q
__device__ __forceinline__ float3 qrot(const Q4 q, const float3 u) {
    float r = rsqrtf(q.w*q.w + q.x*q.x + q.y*q.y + q.z*q.z);
    float w = q.w * r;
    float3 v = make_float3(q.x*r, q.y*r, q.z*r);
    float3 t  = cross3(v, u);
    float3 t2 = cross3(v, t);
    return make_float3(u.x + 2.0f*(w*t.x + t2.x),
                       u.y + 2.0f*(w*t.y + t2.y),
                       u.z + 2.0f*(w*t2.x*0.0f + w*t.z + t2.z)); // placeholder avoided below
}

// NOTE: the placeholder line above would be wrong; define the real qrot here.
__device__ __forceinline__ float3 qrot_correct(const Q4 q, const float3 u) {
    float r = rsqrtf(q.w*q.w + q.x*q.x + q.y*q.y + q.z*q.z);
    float w = q.w * r;
    float3 v = make_float3(q.x*r, q.y*r, q.z*r);
    float3 t  = cross3(v, u);
    float3 t2 = cross3(v, t);
    return make_float3(u.x + 2.0f*(w*t.x + t2.x),
                       u.y + 2.0f*(w*t.y + t2.y),
                       u.z + 2.0f*(w*t.z + t2.z));
}

__global__ __launch_bounds__(256) void rod_frames_kernel(
    const float* __restrict__ verts,       // (B, 129, 3)
    const float* __restrict__ init_direct, // (B, 3)
    const float* __restrict__ m_theta,     // (B, 128)
    const float* __restrict__ edge_mask,   // (B, 128, 1)
    const float* __restrict__ restL,       // (B, 128)
    float* __restrict__ out)               // (B, 128, 5, 3)
{
    __shared__ __align__(16) float lds[RODS_PER_BLOCK * NE * 15]; // 7680 floats, reused for verts stage
    const int tid = threadIdx.x;
    const int wv  = tid >> 6;      // wave id = rod-in-block
    const int l   = tid & 63;      // lane: handles edges 2l, 2l+1
    const int b0  = blockIdx.x * RODS_PER_BLOCK;
    const int b   = b0 + wv;

    // ---- stage verts (4 consecutive rods = contiguous 1548 floats = 387 float4) ----
    {
        const v4f* src4 = (const v4f*)(verts + (size_t)b0 * (NV*3)); // 6192B-aligned
        v4f* dst4 = (v4f*)lds;
        // 387 = 256 + 131
        dst4[tid] = src4[tid];
        if (tid < 131) dst4[256 + tid] = src4[256 + tid];
    }
    __syncthreads();

    float v[9];
    #pragma unroll
    for (int k = 0; k < 9; ++k) v[k] = lds[wv * (NV*3) + 6*l + k];
    __syncthreads();  // verts LDS region will be reused for output staging

    // edges 2l and 2l+1
    float3 eLo = make_float3(v[3]-v[0], v[4]-v[1], v[5]-v[2]);
    float3 eHi = make_float3(v[6]-v[3], v[7]-v[4], v[8]-v[5]);

    // rest lengths (coalesced float2)
    const float2 L2 = ((const float2*)(restL + (size_t)b * NE))[l];
    float Llo = L2.x, Lhi = L2.y;
    float Lprev = __shfl_up(Lhi, 1, 64);          // L[2l-1]
    float3 ePrev;
    ePrev.x = __shfl_up(eHi.x, 1, 64);
    ePrev.y = __shfl_up(eHi.y, 1, 64);
    ePrev.z = __shfl_up(eHi.z, 1, 64);            // edge 2l-1

    // kb for both edges
    float3 kbLo;
    if (l == 0) {
        kbLo = make_float3(0.f, 0.f, 0.f);        // kb[0] = 0
    } else {
        float den = Lprev * Llo + dot3(ePrev, eLo);
        float3 c = cross3(ePrev, eLo);
        float s = 2.0f / den;
        kbLo = make_float3(s*c.x, s*c.y, s*c.z);
    }
    float3 kbHi;
    {
        float den = Llo * Lhi + dot3(eLo, eHi);
        float3 c = cross3(eLo, eHi);
        float s = 2.0f / den;
        kbHi = make_float3(s*c.x, s*c.y, s*c.z);
    }

    // u0 = normalize(cross(cross(e0, init_direct), e0)); e0 = edge 0 (lane 0's eLo)
    float3 e0;
    e0.x = __shfl(eLo.x, 0, 64);
    e0.y = __shfl(eLo.y, 0, 64);
    e0.z = __shfl(eLo.z, 0, 64);
    float3 ind = make_float3(init_direct[(size_t)b*3 + 0],
                             init_direct[(size_t)b*3 + 1],
                             init_direct[(size_t)b*3 + 2]);
    float3 N0 = cross3(e0, ind);
    float3 u0 = cross3(N0, e0);
    {
        float n = sqrtf(dot3(u0, u0));
        float r = 1.0f / fmaxf(n, 1e-12f);
        u0 = make_float3(u0.x*r, u0.y*r, u0.z*r);
    }

    // per-edge quaternions; identity where (1-cosPhi)<=ERR (incl. edge 0)
    Q4 qLo = quat_from_kb(kbLo);
    Q4 qHi = quat_from_kb(kbHi);

    // wave-level inclusive prefix product: Q_e = q_e ⊗ ... ⊗ q_1
    Q4 T = qmul(qHi, qLo);      // this lane's pair product
    Q4 P = T;
    #pragma unroll
    for (int off = 1; off < 64; off <<= 1) {
        Q4 o = qshfl_up(P, off);
        if (l >= off) P = qmul(P, o);
    }
    Q4 E = qshfl_up(P, 1);      // exclusive prefix
    if (l == 0) E = qident();
    Q4 QLo = qmul(qLo, E);      // prefix through edge 2l
    Q4 QHi = qmul(qHi, QLo);    // prefix through edge 2l+1

    // material frame per edge
    float3 buLo = qrot_correct(QLo, u0);
    float3 buHi = qrot_correct(QHi, u0);

    float3 bvLo = cross3(eLo, buLo);
    { float n = sqrtf(dot3(bvLo,bvLo)); float r = 1.0f/fmaxf(n,1e-12f); bvLo = make_float3(bvLo.x*r,bvLo.y*r,bvLo.z*r); }
    float3 bvHi = cross3(eHi, buHi);
    { float n = sqrtf(dot3(bvHi,bvHi)); float r = 1.0f/fmaxf(n,1e-12f); bvHi = make_float3(bvHi.x*r,bvHi.y*r,bvHi.z*r); }

    const float2 M2 = ((const float2*)(edge_mask + (size_t)b * NE))[l];
    buLo.x *= M2.x; buLo.y *= M2.x; buLo.z *= M2.x;
    bvLo.x *= M2.x; bvLo.y *= M2.x; bvLo.z *= M2.x;
    buHi.x *= M2.y; buHi.y *= M2.y; buHi.z *= M2.y;
    bvHi.x *= M2.y; bvHi.y *= M2.y; bvHi.z *= M2.y;

    const float2 TH = ((const float2*)(m_theta + (size_t)b * NE))[l];
    float sLo, cLo, sHi, cHi;
    __sincosf(TH.x, &sLo, &cLo);
    __sincosf(TH.y, &sHi, &cHi);

    float3 m1Lo = make_float3(cLo*buLo.x + sLo*bvLo.x, cLo*buLo.y + sLo*bvLo.y, cLo*buLo.z + sLo*bvLo.z);
    float3 m2Lo = make_float3(-sLo*buLo.x + cLo*bvLo.x, -sLo*buLo.y + cLo*bvLo.y, -sLo*buLo.z + cLo*bvLo.z);
    float3 m1Hi = make_float3(cHi*buHi.x + sHi*bvHi.x, cHi*buHi.y + sHi*bvHi.y, cHi*buHi.z + sHi*bvHi.z);
    float3 m2Hi = make_float3(-sHi*buHi.x + cHi*bvHi.x, -sHi*buHi.y + cHi*bvHi.y, -sHi*buHi.z + cHi*bvHi.z);

    // ---- stage output: rod wv, edges 2l / 2l+1, layout (e,5,3) ----
    float* o = lds + wv * (NE*15) + 30*l;
    o[0]=buLo.x; o[1]=buLo.y; o[2]=buLo.z;
    o[3]=bvLo.x; o[4]=bvLo.y; o[5]=bvLo.z;
    o[6]=kbLo.x; o[7]=kbLo.y; o[8]=kbLo.z;
    o[9]=m1Lo.x; o[10]=m1Lo.y; o[11]=m1Lo.z;
    o[12]=m2Lo.x; o[13]=m2Lo.y; o[14]=m2Lo.z;
    o[15]=buHi.x; o[16]=buHi.y; o[17]=buHi.z;
    o[18]=bvHi.x; o[19]=bvHi.y; o[20]=bvHi.z;
    o[21]=kbHi.x; o[22]=kbHi.y; o[23]=kbHi.z;
    o[24]=m1Hi.x; o[25]=m1Hi.y; o[26]=m1Hi.z;
    o[27]=m2Hi.x; o[28]=m2Hi.y; o[29]=m2Hi.z;
    __syncthreads();

    // ---- coalesced nontemporal float4 copy-out: 4 rods' outputs contiguous ----
    const v4f* s4 = (const v4f*)lds;
    v4f* o4 = (v4f*)(out + (size_t)b0 * (NE*15));
    #pragma unroll
    for (int j = 0; j < RODS_PER_BLOCK * NE * 15 / 4 / 256; ++j) {   // 480 iters of 256... actually 1920/256 = 7.5 → use runtime loop
    }
    for (int i = tid; i < RODS_PER_BLOCK * NE * 15 / 4; i += 256)
        __builtin_nontemporal_store(s4[i], o4 + i);
}

extern "C" void kernel_launch(void* const* d_in, const int* in_sizes, int n_in,
                              void* d_out, int out_size, void* d_ws, size_t ws_size,
                              hipStream_t stream) {
    const float* verts  = (const float*)d_in[0];
    const float* initd  = (const float*)d_in[1];
    const float* mtheta = (const float*)d_in[2];
    const float* emask  = (const float*)d_in[3];
    const float* restL  = (const float*)d_in[4];
    float* out = (float*)d_out;
    dim3 grid(NB / RODS_PER_BLOCK);   // 6144 blocks
    rod_frames_kernel<<<grid, 256, 0, stream>>>(verts, initd, mtheta, emask, restL, out);
}